// Round 4
// baseline (551.412 us; speedup 1.0000x reference)
//
#include <hip/hip_runtime.h>
#include <stdint.h>

// Problem shape (fixed by reference): M=8192 (8 shards x 1024), K=N=4096.
// C[m,n] = sum_k A[m,k] * W[n,k]  (weight stored [N,K], transed_weight==0)
// Single fused kernel: reads fp32 A/W, converts to bf16 in-register
// (v_cvt_pk_bf16_f32, RTNE), stages to LDS, MFMA bf16. No cast pass, no ws.
#define K_DIM 4096
#define N_DIM 4096
#define BM 256
#define BN 256
#define NTILES (K_DIM / 64)   // 64 K-tiles of width 64
#define NIT (NTILES / 2)      // 32 main-loop iterations (2 K-tiles each)

typedef short short8 __attribute__((ext_vector_type(8)));      // 8 bf16 (MFMA A/B frag)
typedef float f32x4 __attribute__((ext_vector_type(4)));       // MFMA C/D frag
typedef float f32x4v __attribute__((ext_vector_type(4)));      // native f32 vec for 16B loads
typedef uint32_t u32x4 __attribute__((ext_vector_type(4)));    // 16B LDS store (8 bf16)
typedef unsigned short ushort_t;

// Raw workgroup barrier: NO implied s_waitcnt (unlike __syncthreads), with
// compiler memory fences so LDS reads/writes and global loads cannot be
// hoisted/sunk across phase boundaries.
__device__ __forceinline__ void wgbar() {
    asm volatile("" ::: "memory");
    __builtin_amdgcn_s_barrier();
    asm volatile("" ::: "memory");
}

// ---------------------------------------------------------------------------
// 8-phase 256x256 fused-cast GEMM (B^T layout), BK=64 as 2 kk-slices of 32.
// 512 threads = 8 waves (2 M-rows x 4 N-cols), per-wave output 128x64.
// LDS = 2 dbuf x 2 kk x (256x32 bf16) x {A,B} = 128 KiB.
// LDS layout (read side unchanged from verified rounds): row r of a kk-slice
// = 4 chunks of 16B; physical slot s holds logical k-chunk s ^ ((r>>1)&3)
// (0 bank conflicts verified). Staging is now reg-based: LINEAR fp32 global
// loads (perfect coalescing), cvt_pk to bf16, ds_write_b128 to the SWIZZLED
// slot (write-side swizzle; global_load_lds linear-dest constraint gone).
//
// Region schedule per iteration i (identical to the verified round-1 map;
// writes land within their phase, i.e. strictly earlier than the old async
// global_load_lds writes -> same safety proof holds):
//   ph1: read buf0.kk0 (A mih0 + B), write A(1,1)<-t1.kk1
//   ph2: read buf0.kk0 (A mih1),     write B(1,1)<-t1.kk1
//   ph3: read buf0.kk1 (A mih0 + B), write A(0,0)<-t2.kk0
//   ph4: read buf0.kk1 (A mih1),     write B(0,0)<-t2.kk0
//   ph5: read buf1.kk0 (A mih0 + B), write A(0,1)<-t2.kk1
//   ph6: read buf1.kk0 (A mih1),     write B(0,1)<-t2.kk1
//   ph7: read buf1.kk1 (A mih0 + B), write A(1,0)<-t3.kk0
//   ph8: read buf1.kk1 (A mih1),     write B(1,0)<-t3.kk0
// Staging pipeline: ISSUE (4x global_load_dwordx4 fp32) at phase p feeds the
// CVT+WRITE at phase p+1 (~1 phase ≈ 600cy lead covers L2/L3-warm latency;
// compiler auto-inserts the counted vmcnt before the convert). Single
// 16-float slot (WAR-safe: convert before reissue) keeps VGPR <= 256/wave.
// ---------------------------------------------------------------------------

#define LDS_A(b, kk) (sA + ((b) * 2 + (kk)) * 8192)
#define LDS_B(b, kk) (sB + ((b) * 2 + (kk)) * 8192)

#define LOAD_AF(af, b, kk, mih) { _Pragma("unroll") for (int t = 0; t < 4; ++t) { \
    int row = wm + (mih) * 64 + t * 16 + row16;                                   \
    af[t] = *(const short8*)(LDS_A(b, kk) + row * 32 + ksw * 8); } }

#define LOAD_BF(bfr, b, kk) { _Pragma("unroll") for (int t = 0; t < 4; ++t) {     \
    int row = wn + t * 16 + row16;                                                \
    bfr[t] = *(const short8*)(LDS_B(b, kk) + row * 32 + ksw * 8); } }

#define MFMA16(mih, af, bfr) { __builtin_amdgcn_s_setprio(1);                     \
    _Pragma("unroll") for (int t = 0; t < 4; ++t)                                 \
    _Pragma("unroll") for (int n = 0; n < 4; ++n)                                 \
        acc[(mih) * 4 + t][n] = __builtin_amdgcn_mfma_f32_16x16x32_bf16(          \
            af[t], bfr[n], acc[(mih) * 4 + t][n], 0, 0, 0);                       \
    __builtin_amdgcn_s_setprio(0); }

#define LGKM0() asm volatile("s_waitcnt lgkmcnt(0)")

// ISSUE: 4x 16B linear fp32 loads into the slot (k in element units).
#define ISSUE(base, k) {                                                          \
    const float* _p0 = (base) + off0 + (k);                                       \
    const float* _p1 = (base) + off1 + (k);                                       \
    S0a = *(const f32x4v*)_p0; S0b = *(const f32x4v*)(_p0 + 4);                   \
    S1a = *(const f32x4v*)_p1; S1b = *(const f32x4v*)(_p1 + 4); }

// CVTW: slot -> 16 bf16 (RTNE via v_cvt_pk_bf16_f32) -> 2x ds_write_b128 at
// the swizzled chunk slots. Compiler inserts the vmcnt wait for the slot.
#define CVTW(ldsp) { uint32_t w0, w1, w2, w3, w4, w5, w6, w7;                     \
    asm("v_cvt_pk_bf16_f32 %0, %1, %2" : "=v"(w0) : "v"(S0a[0]), "v"(S0a[1]));    \
    asm("v_cvt_pk_bf16_f32 %0, %1, %2" : "=v"(w1) : "v"(S0a[2]), "v"(S0a[3]));    \
    asm("v_cvt_pk_bf16_f32 %0, %1, %2" : "=v"(w2) : "v"(S0b[0]), "v"(S0b[1]));    \
    asm("v_cvt_pk_bf16_f32 %0, %1, %2" : "=v"(w3) : "v"(S0b[2]), "v"(S0b[3]));    \
    asm("v_cvt_pk_bf16_f32 %0, %1, %2" : "=v"(w4) : "v"(S1a[0]), "v"(S1a[1]));    \
    asm("v_cvt_pk_bf16_f32 %0, %1, %2" : "=v"(w5) : "v"(S1a[2]), "v"(S1a[3]));    \
    asm("v_cvt_pk_bf16_f32 %0, %1, %2" : "=v"(w6) : "v"(S1b[0]), "v"(S1b[1]));    \
    asm("v_cvt_pk_bf16_f32 %0, %1, %2" : "=v"(w7) : "v"(S1b[2]), "v"(S1b[3]));    \
    *(u32x4*)((ldsp) + dst0 * 8) = (u32x4){w0, w1, w2, w3};                       \
    *(u32x4*)((ldsp) + dst1 * 8) = (u32x4){w4, w5, w6, w7}; }

__global__ __launch_bounds__(512, 2) void gemm_fused_f32_8ph(
    const float* __restrict__ A,      // [M][K] fp32
    const float* __restrict__ B,      // [N][K] fp32
    float* __restrict__ C)            // [M][N] fp32
{
    __shared__ ushort_t sA[2 * 2 * 8192];   // 64 KB
    __shared__ ushort_t sB[2 * 2 * 8192];   // 64 KB

    // XCD-aware swizzle: 512 blocks, 8 XCDs, 64 consecutive tiles per XCD;
    // n-fastest within (16 n-tiles/row -> 4 A-panel rows per XCD, L2-friendly).
    const int pid0 = blockIdx.x;
    const int pid  = (pid0 & 7) * (int)(gridDim.x >> 3) + (pid0 >> 3);
    const int pid_n = pid & 15;              // N_DIM/BN = 16
    const int pid_m = pid >> 4;
    const int tile_m = pid_m * BM;
    const int tile_n = pid_n * BN;

    const int lane  = threadIdx.x & 63;
    const int wave  = threadIdx.x >> 6;      // 0..7
    const int wm    = (wave >> 2) * 128;     // 2 wave rows
    const int wn    = (wave & 3) * 64;       // 4 wave cols
    const int row16 = lane & 15;
    const int quad  = lane >> 4;
    const int ksw   = quad ^ ((row16 >> 1) & 3);   // read-side chunk slot

    // Staging geometry: half-tile = 256x32 slice = 1024 16B-bf16-chunks;
    // 512 threads x 2 chunks. LINEAR global chunk c (row r = c>>2, k-chunk
    // g = c&3); LDS dest slot = g ^ ((r>>1)&3) (write-side swizzle).
    const int c0 = wave * 64 + lane;
    const int c1 = c0 + 512;
    const int r0 = c0 >> 2, g0 = c0 & 3;
    const int r1 = c1 >> 2, g1 = c1 & 3;
    const int off0 = r0 * K_DIM + g0 * 8;    // float-element offset in panel
    const int off1 = r1 * K_DIM + g1 * 8;
    const int dst0 = r0 * 4 + (g0 ^ ((r0 >> 1) & 3));  // 16B-chunk index in slice
    const int dst1 = r1 * 4 + (g1 ^ ((r1 >> 1) & 3));

    const float* Af = A + (size_t)tile_m * K_DIM;
    const float* Bf = B + (size_t)tile_n * K_DIM;

    f32x4v S0a, S0b, S1a, S1b;               // single in-flight fp32 slot
    f32x4 acc[8][4] = {};

    // Prologue: fill tile0 (kk0+kk1) + tile1.kk0, then pre-issue (A,t1,kk1)
    // for iter-0 ph1. Serialized pairs (one-time ~1.5us, amortized over 256
    // phases).
    ISSUE(Af, 0);   CVTW(LDS_A(0, 0));
    ISSUE(Bf, 0);   CVTW(LDS_B(0, 0));
    ISSUE(Af, 32);  CVTW(LDS_A(0, 1));
    ISSUE(Bf, 32);  CVTW(LDS_B(0, 1));
    ISSUE(Af, 64);  CVTW(LDS_A(1, 0));
    ISSUE(Bf, 64);  CVTW(LDS_B(1, 0));
    ISSUE(Af, 96);                            // -> ph1 write A(1,1)<-t1.kk1
    LGKM0();                                  // ds_writes complete before publish
    wgbar();

    short8 af[4], bfr[4];

    #pragma unroll 1
    for (int i = 0; i < NIT; ++i) {
        const int t1k = (2 * i + 1) * 64;
        int t2 = 2 * i + 2; if (t2 > NTILES - 1) t2 = NTILES - 1;
        int t3 = 2 * i + 3; if (t3 > NTILES - 1) t3 = NTILES - 1;
        const int k2 = t2 * 64, k3 = t3 * 64;

        // ph1: S holds (A,t1,kk1)
        LOAD_AF(af, 0, 0, 0); LOAD_BF(bfr, 0, 0);
        CVTW(LDS_A(1, 1)); ISSUE(Bf, t1k + 32);
        wgbar(); LGKM0(); MFMA16(0, af, bfr); wgbar();

        // ph2: S holds (B,t1,kk1)
        LOAD_AF(af, 0, 0, 1);
        CVTW(LDS_B(1, 1)); ISSUE(Af, k2);
        wgbar(); LGKM0(); MFMA16(1, af, bfr); wgbar();

        // ph3: S holds (A,t2,kk0)
        LOAD_AF(af, 0, 1, 0); LOAD_BF(bfr, 0, 1);
        CVTW(LDS_A(0, 0)); ISSUE(Bf, k2);
        wgbar(); LGKM0(); MFMA16(0, af, bfr); wgbar();

        // ph4: S holds (B,t2,kk0)
        LOAD_AF(af, 0, 1, 1);
        CVTW(LDS_B(0, 0)); ISSUE(Af, k2 + 32);
        wgbar(); LGKM0(); MFMA16(1, af, bfr); wgbar();

        // ph5: S holds (A,t2,kk1)
        LOAD_AF(af, 1, 0, 0); LOAD_BF(bfr, 1, 0);
        CVTW(LDS_A(0, 1)); ISSUE(Bf, k2 + 32);
        wgbar(); LGKM0(); MFMA16(0, af, bfr); wgbar();

        // ph6: S holds (B,t2,kk1)
        LOAD_AF(af, 1, 0, 1);
        CVTW(LDS_B(0, 1)); ISSUE(Af, k3);
        wgbar(); LGKM0(); MFMA16(1, af, bfr); wgbar();

        // ph7: S holds (A,t3,kk0)
        LOAD_AF(af, 1, 1, 0); LOAD_BF(bfr, 1, 1);
        CVTW(LDS_A(1, 0)); ISSUE(Bf, k3);
        wgbar(); LGKM0(); MFMA16(0, af, bfr); wgbar();

        // ph8: S holds (B,t3,kk0)
        LOAD_AF(af, 1, 1, 1);
        CVTW(LDS_B(1, 0)); ISSUE(Af, k3 + 32);   // -> next iter ph1 (t1'=t3)
        wgbar(); LGKM0(); MFMA16(1, af, bfr); wgbar();
    }

    // Epilogue: C/D layout col=lane&15, row=quad*4+reg (verified). Plain
    // stores (NT dword stores measured +14% WRITE_SIZE, no speedup — reverted).
    #pragma unroll
    for (int mi = 0; mi < 8; ++mi) {
        #pragma unroll
        for (int r = 0; r < 4; ++r) {
            int m = tile_m + wm + mi * 16 + quad * 4 + r;
            float* crow = C + (size_t)m * N_DIM + tile_n + wn;
            #pragma unroll
            for (int n = 0; n < 4; ++n)
                crow[n * 16 + row16] = acc[mi][n][r];
        }
    }
}

// Safety-net fallback (unexpected shape).
__global__ void gemm_naive_f32(const float* __restrict__ A, const float* __restrict__ W,
                               float* __restrict__ C, int m_tot) {
    int n = blockIdx.x * blockDim.x + threadIdx.x;
    int m = blockIdx.y;
    if (n >= N_DIM || m >= m_tot) return;
    const float* a = A + (size_t)m * K_DIM;
    const float* w = W + (size_t)n * K_DIM;
    float s = 0.f;
    for (int k = 0; k < K_DIM; ++k) s += a[k] * w[k];
    C[(size_t)m * N_DIM + n] = s;
}

extern "C" void kernel_launch(void* const* d_in, const int* in_sizes, int n_in,
                              void* d_out, int out_size, void* d_ws, size_t ws_size,
                              hipStream_t stream) {
    const float* a_f32 = (const float*)d_in[0];   // [8192,4096]
    const float* w_f32 = (const float*)d_in[1];   // [4096,4096] ([N,K])
    float* out = (float*)d_out;

    const size_t a_elems = (size_t)in_sizes[0];
    const size_t w_elems = (size_t)in_sizes[1];
    const int m_tot = (int)(a_elems / K_DIM);     // 8192

    if ((m_tot % BM) == 0 && w_elems == (size_t)N_DIM * K_DIM &&
        a_elems == (size_t)m_tot * K_DIM) {
        int nblocks = (N_DIM / BN) * (m_tot / BM);   // 16 x 32 = 512
        gemm_fused_f32_8ph<<<nblocks, 512, 0, stream>>>(a_f32, w_f32, out);
    } else {
        dim3 grid(N_DIM / 256, m_tot);
        gemm_naive_f32<<<grid, 256, 0, stream>>>(a_f32, w_f32, out, m_tot);
    }
}